// Round 1
// baseline (9929.172 us; speedup 1.0000x reference)
//
#include <hip/hip_runtime.h>
#include <cstdint>
#include <cmath>

#define BATCH 1024
#define SEQ   100
#define HD    256
#define HD3   768
#define NEGBIG (-1000000000.0f)

__device__ __forceinline__ float sigmoidf_(float x) { return 1.0f / (1.0f + expf(-x)); }

// GRU cell with h=0: out = (1-z)*n ; gh == b_hh (constant)
__device__ __forceinline__ float gru0(float gr, float gz, float gn, float hr, float hz, float hn) {
    float r = sigmoidf_(gr + hr);
    float z = sigmoidf_(gz + hz);
    float n = tanhf(gn + r * hn);
    return (1.0f - z) * n;
}

// ---------------- init: mean over N of encoder rows, zero mask/ll ----------------
__global__ __launch_bounds__(256) void init_mean_kernel(const float* __restrict__ enc,
                                                        float* __restrict__ meanenc,
                                                        uint8_t* __restrict__ mask,
                                                        float* __restrict__ ll) {
    int b = blockIdx.x, tid = threadIdx.x;
    const float* e = enc + (size_t)b * SEQ * HD + tid;
    float s = 0.f;
    for (int n = 0; n < SEQ; ++n) s += e[(size_t)n * HD];
    meanenc[(size_t)b * HD + tid] = s * (1.0f / SEQ);
    if (tid < 128) mask[b * 128 + tid] = 0;
    if (tid == 0) ll[b] = 0.f;
}

// ---------------- repack W_ih1[:, :256] (stride 257 -> 256) for aligned float4 ----------------
__global__ __launch_bounds__(256) void repack_w1_kernel(const float* __restrict__ W_ih1,
                                                        float* __restrict__ W1p) {
    int j = blockIdx.x, k = threadIdx.x;
    W1p[(size_t)j * HD + k] = W_ih1[(size_t)j * (HD + 1) + k];
}

// ---------------- ref = enc @ W_ref   (M=102400, N=256, K=256) ----------------
__global__ __launch_bounds__(256) void gemm_ref_kernel(const float* __restrict__ A,
                                                       const float* __restrict__ Bm,
                                                       float* __restrict__ C) {
    __shared__ float As[16][68];
    __shared__ float Bs[16][68];
    const int tid = threadIdx.x;
    const int tx = tid & 15, ty = tid >> 4;
    const int mBase = blockIdx.x * 64, nBase = blockIdx.y * 64;
    const int lr = tid >> 2, lc = (tid & 3) << 2;
    const int bkk = tid >> 4, bn4 = (tid & 15) << 2;
    float acc[4][4] = {};
    for (int k0 = 0; k0 < HD; k0 += 16) {
        float4 av = *(const float4*)&A[(size_t)(mBase + lr) * HD + k0 + lc];
        As[lc + 0][lr] = av.x; As[lc + 1][lr] = av.y; As[lc + 2][lr] = av.z; As[lc + 3][lr] = av.w;
        float4 bv = *(const float4*)&Bm[(size_t)(k0 + bkk) * HD + nBase + bn4];
        *(float4*)&Bs[bkk][bn4] = bv;
        __syncthreads();
#pragma unroll
        for (int kk = 0; kk < 16; ++kk) {
            const float4 a4 = *(const float4*)&As[kk][ty << 2];
            const float4 b4 = *(const float4*)&Bs[kk][tx << 2];
            const float ar_[4] = {a4.x, a4.y, a4.z, a4.w};
            const float br_[4] = {b4.x, b4.y, b4.z, b4.w};
#pragma unroll
            for (int i = 0; i < 4; ++i)
#pragma unroll
                for (int j = 0; j < 4; ++j) acc[i][j] = fmaf(ar_[i], br_[j], acc[i][j]);
        }
        __syncthreads();
    }
#pragma unroll
    for (int i = 0; i < 4; ++i) {
        float4 o = make_float4(acc[i][0], acc[i][1], acc[i][2], acc[i][3]);
        *(float4*)&C[(size_t)(mBase + (ty << 2) + i) * HD + nBase + (tx << 2)] = o;
    }
}

// ------- gi1 = gather(enc by sel | meanenc) @ W_ih1[:, :256].T + b_ih1 + D*W_ih1[:,256] -------
// M=1024 (b), N=768, K=256. B transposed (W1p row j contiguous in k).
__global__ __launch_bounds__(256) void gemm_gi1_kernel(const float* __restrict__ enc,
                                                       const float* __restrict__ meanenc,
                                                       const int* __restrict__ sel,
                                                       const float* __restrict__ W1p,
                                                       const float* __restrict__ W_ih1,
                                                       const float* __restrict__ b_ih1,
                                                       float* __restrict__ gi1, int t) {
    __shared__ float As[16][68];
    __shared__ float Bs[16][68];
    const int tid = threadIdx.x;
    const int tx = tid & 15, ty = tid >> 4;
    const int mBase = blockIdx.x * 64, nBase = blockIdx.y * 64;
    const int lr = tid >> 2, lc = (tid & 3) << 2;
    const int brow = mBase + lr;
    const float* arow = (t == 0) ? (meanenc + (size_t)brow * HD)
                                 : (enc + ((size_t)brow * SEQ + sel[brow]) * HD);
    // replicate the reference's iterative D sequence exactly (D entering step t)
    float Dp = 1.0f;
    const float invN = 1.0f / SEQ;
    for (int i = 0; i < t; ++i) Dp -= invN;
    float acc[4][4] = {};
    for (int k0 = 0; k0 < HD; k0 += 16) {
        float4 av = *(const float4*)&arow[k0 + lc];
        As[lc + 0][lr] = av.x; As[lc + 1][lr] = av.y; As[lc + 2][lr] = av.z; As[lc + 3][lr] = av.w;
        float4 bv = *(const float4*)&W1p[(size_t)(nBase + lr) * HD + k0 + lc];
        Bs[lc + 0][lr] = bv.x; Bs[lc + 1][lr] = bv.y; Bs[lc + 2][lr] = bv.z; Bs[lc + 3][lr] = bv.w;
        __syncthreads();
#pragma unroll
        for (int kk = 0; kk < 16; ++kk) {
            const float4 a4 = *(const float4*)&As[kk][ty << 2];
            const float4 b4 = *(const float4*)&Bs[kk][tx << 2];
            const float ar_[4] = {a4.x, a4.y, a4.z, a4.w};
            const float br_[4] = {b4.x, b4.y, b4.z, b4.w};
#pragma unroll
            for (int i = 0; i < 4; ++i)
#pragma unroll
                for (int j = 0; j < 4; ++j) acc[i][j] = fmaf(ar_[i], br_[j], acc[i][j]);
        }
        __syncthreads();
    }
#pragma unroll
    for (int i = 0; i < 4; ++i) {
        float o[4];
#pragma unroll
        for (int j = 0; j < 4; ++j) {
            int col = nBase + (tx << 2) + j;
            o[j] = acc[i][j] + b_ih1[col] + Dp * W_ih1[(size_t)col * (HD + 1) + HD];
        }
        *(float4*)&gi1[(size_t)(mBase + (ty << 2) + i) * HD3 + nBase + (tx << 2)] =
            make_float4(o[0], o[1], o[2], o[3]);
    }
}

// ------- gi2 = gru1(gi1) @ W_ih2.T + b_ih2   (GRU1 fused into A-load) -------
__global__ __launch_bounds__(256) void gemm_gi2_kernel(const float* __restrict__ gi1,
                                                       const float* __restrict__ b_hh1,
                                                       const float* __restrict__ W_ih2,
                                                       const float* __restrict__ b_ih2,
                                                       float* __restrict__ gi2) {
    __shared__ float As[16][68];
    __shared__ float Bs[16][68];
    const int tid = threadIdx.x;
    const int tx = tid & 15, ty = tid >> 4;
    const int mBase = blockIdx.x * 64, nBase = blockIdx.y * 64;
    const int lr = tid >> 2, lc = (tid & 3) << 2;
    float acc[4][4] = {};
    for (int k0 = 0; k0 < HD; k0 += 16) {
        const float* g = gi1 + (size_t)(mBase + lr) * HD3 + k0 + lc;
        float4 gr = *(const float4*)&g[0];
        float4 gz = *(const float4*)&g[HD];
        float4 gn = *(const float4*)&g[2 * HD];
        float4 hr = *(const float4*)&b_hh1[k0 + lc];
        float4 hz = *(const float4*)&b_hh1[HD + k0 + lc];
        float4 hn = *(const float4*)&b_hh1[2 * HD + k0 + lc];
        As[lc + 0][lr] = gru0(gr.x, gz.x, gn.x, hr.x, hz.x, hn.x);
        As[lc + 1][lr] = gru0(gr.y, gz.y, gn.y, hr.y, hz.y, hn.y);
        As[lc + 2][lr] = gru0(gr.z, gz.z, gn.z, hr.z, hz.z, hn.z);
        As[lc + 3][lr] = gru0(gr.w, gz.w, gn.w, hr.w, hz.w, hn.w);
        float4 bv = *(const float4*)&W_ih2[(size_t)(nBase + lr) * HD + k0 + lc];
        Bs[lc + 0][lr] = bv.x; Bs[lc + 1][lr] = bv.y; Bs[lc + 2][lr] = bv.z; Bs[lc + 3][lr] = bv.w;
        __syncthreads();
#pragma unroll
        for (int kk = 0; kk < 16; ++kk) {
            const float4 a4 = *(const float4*)&As[kk][ty << 2];
            const float4 b4 = *(const float4*)&Bs[kk][tx << 2];
            const float ar_[4] = {a4.x, a4.y, a4.z, a4.w};
            const float br_[4] = {b4.x, b4.y, b4.z, b4.w};
#pragma unroll
            for (int i = 0; i < 4; ++i)
#pragma unroll
                for (int j = 0; j < 4; ++j) acc[i][j] = fmaf(ar_[i], br_[j], acc[i][j]);
        }
        __syncthreads();
    }
#pragma unroll
    for (int i = 0; i < 4; ++i) {
        float o[4];
#pragma unroll
        for (int j = 0; j < 4; ++j) o[j] = acc[i][j] + b_ih2[nBase + (tx << 2) + j];
        *(float4*)&gi2[(size_t)(mBase + (ty << 2) + i) * HD3 + nBase + (tx << 2)] =
            make_float4(o[0], o[1], o[2], o[3]);
    }
}

// ------- q = gru2(gi2) @ W_q   (32x32 tiles for block-count; GRU2 fused) -------
__global__ __launch_bounds__(256) void gemm_q_kernel(const float* __restrict__ gi2,
                                                     const float* __restrict__ b_hh2,
                                                     const float* __restrict__ W_q,
                                                     float* __restrict__ qb) {
    __shared__ float As[32][36];
    __shared__ float Bs[32][36];
    const int tid = threadIdx.x;
    const int tx = tid & 15, ty = tid >> 4;
    const int mBase = blockIdx.x * 32, nBase = blockIdx.y * 32;
    const int ar = tid >> 3, ac = (tid & 7) << 2;
    float acc[2][2] = {};
    for (int k0 = 0; k0 < HD; k0 += 32) {
        const float* g = gi2 + (size_t)(mBase + ar) * HD3 + k0 + ac;
        float4 gr = *(const float4*)&g[0];
        float4 gz = *(const float4*)&g[HD];
        float4 gn = *(const float4*)&g[2 * HD];
        float4 hr = *(const float4*)&b_hh2[k0 + ac];
        float4 hz = *(const float4*)&b_hh2[HD + k0 + ac];
        float4 hn = *(const float4*)&b_hh2[2 * HD + k0 + ac];
        As[ac + 0][ar] = gru0(gr.x, gz.x, gn.x, hr.x, hz.x, hn.x);
        As[ac + 1][ar] = gru0(gr.y, gz.y, gn.y, hr.y, hz.y, hn.y);
        As[ac + 2][ar] = gru0(gr.z, gz.z, gn.z, hr.z, hz.z, hn.z);
        As[ac + 3][ar] = gru0(gr.w, gz.w, gn.w, hr.w, hz.w, hn.w);
        float4 bv = *(const float4*)&W_q[(size_t)(k0 + ar) * HD + nBase + ac];
        *(float4*)&Bs[ar][ac] = bv;
        __syncthreads();
#pragma unroll
        for (int kk = 0; kk < 32; ++kk) {
            const float2 a2 = *(const float2*)&As[kk][ty << 1];
            const float2 b2 = *(const float2*)&Bs[kk][tx << 1];
            acc[0][0] = fmaf(a2.x, b2.x, acc[0][0]);
            acc[0][1] = fmaf(a2.x, b2.y, acc[0][1]);
            acc[1][0] = fmaf(a2.y, b2.x, acc[1][0]);
            acc[1][1] = fmaf(a2.y, b2.y, acc[1][1]);
        }
        __syncthreads();
    }
#pragma unroll
    for (int i = 0; i < 2; ++i) {
        *(float2*)&qb[(size_t)(mBase + (ty << 1) + i) * HD + nBase + (tx << 1)] =
            make_float2(acc[i][0], acc[i][1]);
    }
}

// ------- scoring + masked argmax + log-softmax + state update (block per b) -------
__global__ __launch_bounds__(256) void score_kernel(const float* __restrict__ refb,
                                                    const float* __restrict__ qb,
                                                    const float* __restrict__ vvec,
                                                    uint8_t* __restrict__ mask,
                                                    int* __restrict__ sel,
                                                    int* __restrict__ pi,
                                                    float* __restrict__ ll, int t) {
    __shared__ float qs[HD];
    __shared__ float vs[HD];
    __shared__ float us[SEQ];
    const int b = blockIdx.x, tid = threadIdx.x;
    qs[tid] = qb[(size_t)b * HD + tid];
    vs[tid] = vvec[tid];
    __syncthreads();
    const int w = tid >> 6, lane = tid & 63;
    const float4 qv = *(const float4*)&qs[lane << 2];
    const float4 vv = *(const float4*)&vs[lane << 2];
    for (int n = w; n < SEQ; n += 4) {
        const float4 rf = *(const float4*)&refb[((size_t)b * SEQ + n) * HD + (lane << 2)];
        float s = tanhf(qv.x + rf.x) * vv.x;
        s = fmaf(tanhf(qv.y + rf.y), vv.y, s);
        s = fmaf(tanhf(qv.z + rf.z), vv.z, s);
        s = fmaf(tanhf(qv.w + rf.w), vv.w, s);
#pragma unroll
        for (int o = 1; o < 64; o <<= 1) s += __shfl_xor(s, o, 64);
        if (lane == 0) {
            float u = 10.0f * tanhf(s);
            if (mask[b * 128 + n]) u = NEGBIG;
            us[n] = u;
        }
    }
    __syncthreads();
    if (tid < 64) {
        float va = us[tid];
        int ia = tid;
        if (tid + 64 < SEQ) {
            float vb = us[tid + 64];
            if (vb > va) { va = vb; ia = tid + 64; }   // tie keeps smaller index
        }
#pragma unroll
        for (int o = 1; o < 64; o <<= 1) {
            float ov = __shfl_xor(va, o, 64);
            int oi = __shfl_xor(ia, o, 64);
            if (ov > va || (ov == va && oi < ia)) { va = ov; ia = oi; }
        }
        float e = expf(us[tid] - va) + ((tid + 64 < SEQ) ? expf(us[tid + 64] - va) : 0.0f);
#pragma unroll
        for (int o = 1; o < 64; o <<= 1) e += __shfl_xor(e, o, 64);
        if (tid == 0) {
            float logp = -logf(e);   // u[nxt] == va, so log_softmax[nxt] = -log(sum)
            ll[b] += logp;
            mask[b * 128 + ia] = 1;
            sel[b] = ia;
            pi[(size_t)b * SEQ + t] = ia;
        }
    }
}

// ------- final: tour cost from pi + emit (cost, ll) -------
__global__ __launch_bounds__(128) void final_kernel(const float* __restrict__ x,
                                                    const int* __restrict__ pi,
                                                    const float* __restrict__ ll,
                                                    float* __restrict__ out) {
    __shared__ float red[2];
    const int b = blockIdx.x, tid = threadIdx.x;
    const int w = tid >> 6, lane = tid & 63;
    float d = 0.f;
    if (tid < SEQ) {
        int p = pi[(size_t)b * SEQ + tid];
        int pn = pi[(size_t)b * SEQ + ((tid == SEQ - 1) ? 0 : tid + 1)];
        float xa = x[((size_t)b * SEQ + p) * 2 + 0];
        float ya = x[((size_t)b * SEQ + p) * 2 + 1];
        float xb = x[((size_t)b * SEQ + pn) * 2 + 0];
        float yb = x[((size_t)b * SEQ + pn) * 2 + 1];
        float dx = xa - xb, dy = ya - yb;
        d = sqrtf(dx * dx + dy * dy);
    }
#pragma unroll
    for (int o = 1; o < 64; o <<= 1) d += __shfl_xor(d, o, 64);
    if (lane == 0) red[w] = d;
    __syncthreads();
    if (tid == 0) {
        out[b] = red[0] + red[1];
        out[BATCH + b] = ll[b];
    }
}

extern "C" void kernel_launch(void* const* d_in, const int* in_sizes, int n_in,
                              void* d_out, int out_size, void* d_ws, size_t ws_size,
                              hipStream_t stream) {
    const float* x     = (const float*)d_in[0];
    const float* enc   = (const float*)d_in[1];
    const float* W_ih1 = (const float*)d_in[2];
    // d_in[3] = W_hh1: unused (h==0 -> gh == b_hh)
    const float* b_ih1 = (const float*)d_in[4];
    const float* b_hh1 = (const float*)d_in[5];
    const float* W_ih2 = (const float*)d_in[6];
    // d_in[7] = W_hh2: unused
    const float* b_ih2 = (const float*)d_in[8];
    const float* b_hh2 = (const float*)d_in[9];
    const float* W_q   = (const float*)d_in[10];
    const float* W_ref = (const float*)d_in[11];
    const float* v     = (const float*)d_in[12];
    float* out = (float*)d_out;

    char* w = (char*)d_ws;
    size_t off = 0;
    auto take = [&](size_t bytes) {
        char* p = w + off;
        off = (off + bytes + 255) & ~(size_t)255;
        return p;
    };
    float*   refb    = (float*)take((size_t)BATCH * SEQ * HD * 4);   // ~104.9 MB
    float*   meanenc = (float*)take((size_t)BATCH * HD * 4);
    float*   gi1     = (float*)take((size_t)BATCH * HD3 * 4);
    float*   gi2     = (float*)take((size_t)BATCH * HD3 * 4);
    float*   qb      = (float*)take((size_t)BATCH * HD * 4);
    float*   W1p     = (float*)take((size_t)HD3 * HD * 4);
    float*   ll      = (float*)take((size_t)BATCH * 4);
    int*     sel     = (int*)take((size_t)BATCH * 4);
    int*     pi      = (int*)take((size_t)BATCH * SEQ * 4);
    uint8_t* mask    = (uint8_t*)take((size_t)BATCH * 128);
    (void)ws_size; (void)in_sizes; (void)n_in; (void)out_size;

    hipLaunchKernelGGL(init_mean_kernel, dim3(BATCH), dim3(HD), 0, stream, enc, meanenc, mask, ll);
    hipLaunchKernelGGL(repack_w1_kernel, dim3(HD3), dim3(HD), 0, stream, W_ih1, W1p);
    hipLaunchKernelGGL(gemm_ref_kernel, dim3(BATCH * SEQ / 64, HD / 64), dim3(256), 0, stream,
                       enc, W_ref, refb);
    for (int t = 0; t < SEQ; ++t) {
        hipLaunchKernelGGL(gemm_gi1_kernel, dim3(BATCH / 64, HD3 / 64), dim3(256), 0, stream,
                           enc, meanenc, sel, W1p, W_ih1, b_ih1, gi1, t);
        hipLaunchKernelGGL(gemm_gi2_kernel, dim3(BATCH / 64, HD3 / 64), dim3(256), 0, stream,
                           gi1, b_hh1, W_ih2, b_ih2, gi2);
        hipLaunchKernelGGL(gemm_q_kernel, dim3(BATCH / 32, HD / 32), dim3(256), 0, stream,
                           gi2, b_hh2, W_q, qb);
        hipLaunchKernelGGL(score_kernel, dim3(BATCH), dim3(256), 0, stream,
                           refb, qb, v, mask, sel, pi, ll, t);
    }
    hipLaunchKernelGGL(final_kernel, dim3(BATCH), dim3(128), 0, stream, x, pi, ll, out);
}

// Round 2
// 7444.779 us; speedup vs baseline: 1.3337x; 1.3337x over previous
//
#include <hip/hip_runtime.h>
#include <cstdint>
#include <cmath>

#define BATCH 1024
#define SEQ   100
#define HD    256
#define HD3   768
#define PW    1024   // row width of fused P = [ref(256) | G1(768)]

__device__ __forceinline__ float sigmoidf_(float x) { return 1.0f / (1.0f + expf(-x)); }

// GRU cell with h=0: out = (1-z)*n ; gh == b_hh (constant)
__device__ __forceinline__ float gru0(float gr, float gz, float gn, float hr, float hz, float hn) {
    float r = sigmoidf_(gr + hr);
    float z = sigmoidf_(gz + hz);
    float n = tanhf(gn + r * hn);
    return (1.0f - z) * n;
}

// ---------------- init: mean over N of encoder rows, rem list, zero ll ----------------
__global__ __launch_bounds__(256) void init_mean_kernel(const float* __restrict__ enc,
                                                        float* __restrict__ meanenc,
                                                        int* __restrict__ rem,
                                                        float* __restrict__ ll) {
    int b = blockIdx.x, tid = threadIdx.x;
    const float* e = enc + (size_t)b * SEQ * HD + tid;
    float s = 0.f;
    for (int n = 0; n < SEQ; ++n) s += e[(size_t)n * HD];
    meanenc[(size_t)b * HD + tid] = s * (1.0f / SEQ);
    if (tid < SEQ) rem[b * SEQ + tid] = tid;
    if (tid == 0) ll[b] = 0.f;
}

// ---- prep: Bc[k][0:256]=W_ref[k][:], Bc[k][256+j]=W_ih1[j][k]; biasc; wl=W_ih1[:,256] ----
__global__ __launch_bounds__(256) void prep_kernel(const float* __restrict__ W_ref,
                                                   const float* __restrict__ W_ih1,
                                                   const float* __restrict__ b_ih1,
                                                   float* __restrict__ Bc,
                                                   float* __restrict__ biasc,
                                                   float* __restrict__ wl) {
    int k = blockIdx.x, tid = threadIdx.x;
    Bc[(size_t)k * PW + tid] = W_ref[(size_t)k * HD + tid];
#pragma unroll
    for (int c = 0; c < 3; ++c) {
        int j = c * HD + tid;
        Bc[(size_t)k * PW + HD + j] = W_ih1[(size_t)j * (HD + 1) + k];
    }
    if (k == 0) {
        biasc[tid] = 0.f;
#pragma unroll
        for (int c = 0; c < 3; ++c) {
            int j = c * HD + tid;
            biasc[HD + j] = b_ih1[j];
            wl[j] = W_ih1[(size_t)j * (HD + 1) + HD];
        }
    }
}

// ------------- generic C = A(lda) @ B(ldb, K x N) + bias, K=256, 64x64 tiles -------------
__global__ __launch_bounds__(256) void gemm_bias_kernel(const float* __restrict__ A, int lda,
                                                        const float* __restrict__ Bm, int ldb,
                                                        const float* __restrict__ bias,
                                                        float* __restrict__ C, int ldc) {
    __shared__ float As[16][68];
    __shared__ float Bs[16][68];
    const int tid = threadIdx.x;
    const int tx = tid & 15, ty = tid >> 4;
    const int mBase = blockIdx.x * 64, nBase = blockIdx.y * 64;
    const int lr = tid >> 2, lc = (tid & 3) << 2;
    const int bkk = tid >> 4, bn4 = (tid & 15) << 2;
    float acc[4][4] = {};
    for (int k0 = 0; k0 < HD; k0 += 16) {
        float4 av = *(const float4*)&A[(size_t)(mBase + lr) * lda + k0 + lc];
        As[lc + 0][lr] = av.x; As[lc + 1][lr] = av.y; As[lc + 2][lr] = av.z; As[lc + 3][lr] = av.w;
        float4 bv = *(const float4*)&Bm[(size_t)(k0 + bkk) * ldb + nBase + bn4];
        *(float4*)&Bs[bkk][bn4] = bv;
        __syncthreads();
#pragma unroll
        for (int kk = 0; kk < 16; ++kk) {
            const float4 a4 = *(const float4*)&As[kk][ty << 2];
            const float4 b4 = *(const float4*)&Bs[kk][tx << 2];
            const float ar_[4] = {a4.x, a4.y, a4.z, a4.w};
            const float br_[4] = {b4.x, b4.y, b4.z, b4.w};
#pragma unroll
            for (int i = 0; i < 4; ++i)
#pragma unroll
                for (int j = 0; j < 4; ++j) acc[i][j] = fmaf(ar_[i], br_[j], acc[i][j]);
        }
        __syncthreads();
    }
#pragma unroll
    for (int i = 0; i < 4; ++i) {
        float o[4];
#pragma unroll
        for (int j = 0; j < 4; ++j) o[j] = acc[i][j] + bias[nBase + (tx << 2) + j];
        *(float4*)&C[(size_t)(mBase + (ty << 2) + i) * ldc + nBase + (tx << 2)] =
            make_float4(o[0], o[1], o[2], o[3]);
    }
}

// ------- fallback: gi1 = gather(enc by sel | meanenc) @ Bc[:,256:] + b_ih1 -------
__global__ __launch_bounds__(256) void gemm_gather_kernel(const float* __restrict__ enc,
                                                          const float* __restrict__ meanenc,
                                                          const int* __restrict__ sel,
                                                          const float* __restrict__ Bm,  // Bc+HD
                                                          const float* __restrict__ bias, // biasc+HD
                                                          float* __restrict__ C, int t) {
    __shared__ float As[16][68];
    __shared__ float Bs[16][68];
    const int tid = threadIdx.x;
    const int tx = tid & 15, ty = tid >> 4;
    const int mBase = blockIdx.x * 64, nBase = blockIdx.y * 64;
    const int lr = tid >> 2, lc = (tid & 3) << 2;
    const int brow = mBase + lr;
    const float* arow = (t == 0) ? (meanenc + (size_t)brow * HD)
                                 : (enc + ((size_t)brow * SEQ + sel[brow]) * HD);
    const int bkk = tid >> 4, bn4 = (tid & 15) << 2;
    float acc[4][4] = {};
    for (int k0 = 0; k0 < HD; k0 += 16) {
        float4 av = *(const float4*)&arow[k0 + lc];
        As[lc + 0][lr] = av.x; As[lc + 1][lr] = av.y; As[lc + 2][lr] = av.z; As[lc + 3][lr] = av.w;
        float4 bv = *(const float4*)&Bm[(size_t)(k0 + bkk) * PW + nBase + bn4];
        *(float4*)&Bs[bkk][bn4] = bv;
        __syncthreads();
#pragma unroll
        for (int kk = 0; kk < 16; ++kk) {
            const float4 a4 = *(const float4*)&As[kk][ty << 2];
            const float4 b4 = *(const float4*)&Bs[kk][tx << 2];
            const float ar_[4] = {a4.x, a4.y, a4.z, a4.w};
            const float br_[4] = {b4.x, b4.y, b4.z, b4.w};
#pragma unroll
            for (int i = 0; i < 4; ++i)
#pragma unroll
                for (int j = 0; j < 4; ++j) acc[i][j] = fmaf(ar_[i], br_[j], acc[i][j]);
        }
        __syncthreads();
    }
#pragma unroll
    for (int i = 0; i < 4; ++i) {
        float o[4];
#pragma unroll
        for (int j = 0; j < 4; ++j) o[j] = acc[i][j] + bias[nBase + (tx << 2) + j];
        *(float4*)&C[(size_t)(mBase + (ty << 2) + i) * HD3 + nBase + (tx << 2)] =
            make_float4(o[0], o[1], o[2], o[3]);
    }
}

// ------- h1 = gru1(gi1 + D_t*wl)  (t subtractions for D) -------
__global__ __launch_bounds__(256) void h1_kernel(const float* __restrict__ gi1,
                                                 const float* __restrict__ wl,
                                                 const float* __restrict__ bhh1,
                                                 float* __restrict__ h1, int t) {
    const int b = blockIdx.x, tid = threadIdx.x;
    float D = 1.0f;
    const float invN = 1.0f / SEQ;
    for (int i = 0; i < t; ++i) D -= invN;
    const float* g = gi1 + (size_t)b * HD3;
    float gr = g[tid] + D * wl[tid];
    float gz = g[tid + HD] + D * wl[tid + HD];
    float gn = g[tid + 2 * HD] + D * wl[tid + 2 * HD];
    h1[(size_t)b * HD + tid] = gru0(gr, gz, gn, bhh1[tid], bhh1[tid + HD], bhh1[tid + 2 * HD]);
}

// ------- gi2 = h1 @ W_ih2.T + b_ih2 -------
__global__ __launch_bounds__(256) void gemm_gi2_kernel(const float* __restrict__ h1,
                                                       const float* __restrict__ W_ih2,
                                                       const float* __restrict__ b_ih2,
                                                       float* __restrict__ gi2) {
    __shared__ float As[16][68];
    __shared__ float Bs[16][68];
    const int tid = threadIdx.x;
    const int tx = tid & 15, ty = tid >> 4;
    const int mBase = blockIdx.x * 64, nBase = blockIdx.y * 64;
    const int lr = tid >> 2, lc = (tid & 3) << 2;
    float acc[4][4] = {};
    for (int k0 = 0; k0 < HD; k0 += 16) {
        float4 av = *(const float4*)&h1[(size_t)(mBase + lr) * HD + k0 + lc];
        As[lc + 0][lr] = av.x; As[lc + 1][lr] = av.y; As[lc + 2][lr] = av.z; As[lc + 3][lr] = av.w;
        float4 bv = *(const float4*)&W_ih2[(size_t)(nBase + lr) * HD + k0 + lc];
        Bs[lc + 0][lr] = bv.x; Bs[lc + 1][lr] = bv.y; Bs[lc + 2][lr] = bv.z; Bs[lc + 3][lr] = bv.w;
        __syncthreads();
#pragma unroll
        for (int kk = 0; kk < 16; ++kk) {
            const float4 a4 = *(const float4*)&As[kk][ty << 2];
            const float4 b4 = *(const float4*)&Bs[kk][tx << 2];
            const float ar_[4] = {a4.x, a4.y, a4.z, a4.w};
            const float br_[4] = {b4.x, b4.y, b4.z, b4.w};
#pragma unroll
            for (int i = 0; i < 4; ++i)
#pragma unroll
                for (int j = 0; j < 4; ++j) acc[i][j] = fmaf(ar_[i], br_[j], acc[i][j]);
        }
        __syncthreads();
    }
#pragma unroll
    for (int i = 0; i < 4; ++i) {
        float o[4];
#pragma unroll
        for (int j = 0; j < 4; ++j) o[j] = acc[i][j] + b_ih2[nBase + (tx << 2) + j];
        *(float4*)&gi2[(size_t)(mBase + (ty << 2) + i) * HD3 + nBase + (tx << 2)] =
            make_float4(o[0], o[1], o[2], o[3]);
    }
}

// ------- q = gru2(gi2) @ W_q   (32x32 tiles; GRU2 fused into A-load) -------
__global__ __launch_bounds__(256) void gemm_q_kernel(const float* __restrict__ gi2,
                                                     const float* __restrict__ b_hh2,
                                                     const float* __restrict__ W_q,
                                                     float* __restrict__ qb) {
    __shared__ float As[32][36];
    __shared__ float Bs[32][36];
    const int tid = threadIdx.x;
    const int tx = tid & 15, ty = tid >> 4;
    const int mBase = blockIdx.x * 32, nBase = blockIdx.y * 32;
    const int ar = tid >> 3, ac = (tid & 7) << 2;
    float acc[2][2] = {};
    for (int k0 = 0; k0 < HD; k0 += 32) {
        const float* g = gi2 + (size_t)(mBase + ar) * HD3 + k0 + ac;
        float4 gr = *(const float4*)&g[0];
        float4 gz = *(const float4*)&g[HD];
        float4 gn = *(const float4*)&g[2 * HD];
        float4 hr = *(const float4*)&b_hh2[k0 + ac];
        float4 hz = *(const float4*)&b_hh2[HD + k0 + ac];
        float4 hn = *(const float4*)&b_hh2[2 * HD + k0 + ac];
        As[ac + 0][ar] = gru0(gr.x, gz.x, gn.x, hr.x, hz.x, hn.x);
        As[ac + 1][ar] = gru0(gr.y, gz.y, gn.y, hr.y, hz.y, hn.y);
        As[ac + 2][ar] = gru0(gr.z, gz.z, gn.z, hr.z, hz.z, hn.z);
        As[ac + 3][ar] = gru0(gr.w, gz.w, gn.w, hr.w, hz.w, hn.w);
        float4 bv = *(const float4*)&W_q[(size_t)(k0 + ar) * HD + nBase + ac];
        *(float4*)&Bs[ar][ac] = bv;
        __syncthreads();
#pragma unroll
        for (int kk = 0; kk < 32; ++kk) {
            const float2 a2 = *(const float2*)&As[kk][ty << 1];
            const float2 b2 = *(const float2*)&Bs[kk][tx << 1];
            acc[0][0] = fmaf(a2.x, b2.x, acc[0][0]);
            acc[0][1] = fmaf(a2.x, b2.y, acc[0][1]);
            acc[1][0] = fmaf(a2.y, b2.x, acc[1][0]);
            acc[1][1] = fmaf(a2.y, b2.y, acc[1][1]);
        }
        __syncthreads();
    }
#pragma unroll
    for (int i = 0; i < 2; ++i) {
        *(float2*)&qb[(size_t)(mBase + (ty << 1) + i) * HD + nBase + (tx << 1)] =
            make_float2(acc[i][0], acc[i][1]);
    }
}

// --- score: compacted scoring + argmax + log-softmax + state update (+h1 epilogue) ---
__global__ __launch_bounds__(256) void score_kernel(const float* __restrict__ refbase, int ldref,
                                                    const float* __restrict__ qb,
                                                    const float* __restrict__ vvec,
                                                    int* __restrict__ rem,
                                                    int* __restrict__ sel,
                                                    int* __restrict__ pi,
                                                    float* __restrict__ ll,
                                                    const float* __restrict__ wl,
                                                    const float* __restrict__ bhh1,
                                                    float* __restrict__ h1,
                                                    int t, int do_h1) {
    __shared__ float qs[HD];
    __shared__ float vs[HD];
    __shared__ float us[SEQ];
    __shared__ int ns[SEQ];
    __shared__ int nsel_s;
    const int b = blockIdx.x, tid = threadIdx.x;
    const int cnt = SEQ - t;
    qs[tid] = qb[(size_t)b * HD + tid];
    vs[tid] = vvec[tid];
    __syncthreads();
    const int w = tid >> 6, lane = tid & 63;
    const float4 qv = *(const float4*)&qs[lane << 2];
    const float4 vv = *(const float4*)&vs[lane << 2];
    for (int j = w; j < cnt; j += 4) {
        int n = rem[b * SEQ + j];
        const float4 rf = *(const float4*)&refbase[((size_t)b * SEQ + n) * ldref + (lane << 2)];
        float s = tanhf(qv.x + rf.x) * vv.x;
        s = fmaf(tanhf(qv.y + rf.y), vv.y, s);
        s = fmaf(tanhf(qv.z + rf.z), vv.z, s);
        s = fmaf(tanhf(qv.w + rf.w), vv.w, s);
#pragma unroll
        for (int o = 1; o < 64; o <<= 1) s += __shfl_xor(s, o, 64);
        if (lane == 0) {
            us[j] = 10.0f * tanhf(s);
            ns[j] = n;
        }
    }
    __syncthreads();
    if (tid < 64) {
        float va = (tid < cnt) ? us[tid] : -3.0e38f;
        int ia = tid;
        if (tid + 64 < cnt) {
            float vb = us[tid + 64];
            if (vb > va) { va = vb; ia = tid + 64; }
        }
#pragma unroll
        for (int o = 1; o < 64; o <<= 1) {
            float ov = __shfl_xor(va, o, 64);
            int oi = __shfl_xor(ia, o, 64);
            if (ov > va || (ov == va && oi < ia)) { va = ov; ia = oi; }
        }
        float e = ((tid < cnt) ? expf(us[tid] - va) : 0.0f) +
                  ((tid + 64 < cnt) ? expf(us[tid + 64] - va) : 0.0f);
#pragma unroll
        for (int o = 1; o < 64; o <<= 1) e += __shfl_xor(e, o, 64);
        if (tid == 0) {
            int n = ns[ia];
            ll[b] += -logf(e);        // u[sel] == max, so log_softmax[sel] = -log(sum)
            sel[b] = n;
            pi[(size_t)b * SEQ + t] = n;
            rem[b * SEQ + ia] = rem[b * SEQ + cnt - 1];  // swap-remove
            nsel_s = n;
        }
    }
    __syncthreads();
    if (do_h1) {   // compute h1 for step t+1 (G1 path only: ldref==PW)
        const int n = nsel_s;
        const float* g1 = refbase + ((size_t)b * SEQ + n) * ldref + HD;
        float D = 1.0f;
        const float invN = 1.0f / SEQ;
        for (int i = 0; i <= t; ++i) D -= invN;
        float gr = g1[tid] + D * wl[tid];
        float gz = g1[tid + HD] + D * wl[tid + HD];
        float gn = g1[tid + 2 * HD] + D * wl[tid + 2 * HD];
        h1[(size_t)b * HD + tid] =
            gru0(gr, gz, gn, bhh1[tid], bhh1[tid + HD], bhh1[tid + 2 * HD]);
    }
}

// ------- final: tour cost from pi + emit (cost, ll) -------
__global__ __launch_bounds__(128) void final_kernel(const float* __restrict__ x,
                                                    const int* __restrict__ pi,
                                                    const float* __restrict__ ll,
                                                    float* __restrict__ out) {
    __shared__ float red[2];
    const int b = blockIdx.x, tid = threadIdx.x;
    const int w = tid >> 6, lane = tid & 63;
    float d = 0.f;
    if (tid < SEQ) {
        int p = pi[(size_t)b * SEQ + tid];
        int pn = pi[(size_t)b * SEQ + ((tid == SEQ - 1) ? 0 : tid + 1)];
        float xa = x[((size_t)b * SEQ + p) * 2 + 0];
        float ya = x[((size_t)b * SEQ + p) * 2 + 1];
        float xb = x[((size_t)b * SEQ + pn) * 2 + 0];
        float yb = x[((size_t)b * SEQ + pn) * 2 + 1];
        float dx = xa - xb, dy = ya - yb;
        d = sqrtf(dx * dx + dy * dy);
    }
#pragma unroll
    for (int o = 1; o < 64; o <<= 1) d += __shfl_xor(d, o, 64);
    if (lane == 0) red[w] = d;
    __syncthreads();
    if (tid == 0) {
        out[b] = red[0] + red[1];
        out[BATCH + b] = ll[b];
    }
}

extern "C" void kernel_launch(void* const* d_in, const int* in_sizes, int n_in,
                              void* d_out, int out_size, void* d_ws, size_t ws_size,
                              hipStream_t stream) {
    const float* x     = (const float*)d_in[0];
    const float* enc   = (const float*)d_in[1];
    const float* W_ih1 = (const float*)d_in[2];
    // d_in[3] = W_hh1: unused (h==0 -> gh == b_hh)
    const float* b_ih1 = (const float*)d_in[4];
    const float* b_hh1 = (const float*)d_in[5];
    const float* W_ih2 = (const float*)d_in[6];
    // d_in[7] = W_hh2: unused
    const float* b_ih2 = (const float*)d_in[8];
    const float* b_hh2 = (const float*)d_in[9];
    const float* W_q   = (const float*)d_in[10];
    const float* W_ref = (const float*)d_in[11];
    const float* v     = (const float*)d_in[12];
    float* out = (float*)d_out;
    (void)in_sizes; (void)n_in; (void)out_size;

    char* w = (char*)d_ws;
    size_t off = 0;
    auto take = [&](size_t bytes) {
        char* p = w + off;
        off = (off + bytes + 255) & ~(size_t)255;
        return p;
    };
    float* meanenc = (float*)take((size_t)BATCH * HD * 4);
    float* gi1     = (float*)take((size_t)BATCH * HD3 * 4);
    float* gi2     = (float*)take((size_t)BATCH * HD3 * 4);
    float* qb      = (float*)take((size_t)BATCH * HD * 4);
    float* h1      = (float*)take((size_t)BATCH * HD * 4);
    float* Bc      = (float*)take((size_t)HD * PW * 4);
    float* biasc   = (float*)take((size_t)PW * 4);
    float* wl      = (float*)take((size_t)HD3 * 4);
    float* ll      = (float*)take((size_t)BATCH * 4);
    int*   sel     = (int*)take((size_t)BATCH * 4);
    int*   pi      = (int*)take((size_t)BATCH * SEQ * 4);
    int*   rem     = (int*)take((size_t)BATCH * SEQ * 4);

    const size_t Pbytes = (size_t)BATCH * SEQ * PW * 4;     // 419.4 MB
    const size_t Rbytes = (size_t)BATCH * SEQ * HD * 4;     // 104.9 MB
    const bool useG1 = (ws_size >= off + Pbytes);
    float* P    = useG1 ? (float*)take(Pbytes) : nullptr;
    float* refb = useG1 ? nullptr : (float*)take(Rbytes);

    hipLaunchKernelGGL(init_mean_kernel, dim3(BATCH), dim3(HD), 0, stream, enc, meanenc, rem, ll);
    hipLaunchKernelGGL(prep_kernel, dim3(HD), dim3(HD), 0, stream, W_ref, W_ih1, b_ih1, Bc, biasc, wl);

    if (useG1) {
        // P = enc @ [W_ref | W1^T] + [0 | b_ih1]   (102400 x 1024 x 256)
        hipLaunchKernelGGL(gemm_bias_kernel, dim3(BATCH * SEQ / 64, PW / 64), dim3(256), 0, stream,
                           enc, HD, Bc, PW, biasc, P, PW);
        // gi1 for t=0 (mean context), then h1_0
        hipLaunchKernelGGL(gemm_bias_kernel, dim3(BATCH / 64, HD3 / 64), dim3(256), 0, stream,
                           meanenc, HD, Bc + HD, PW, biasc + HD, gi1, HD3);
        hipLaunchKernelGGL(h1_kernel, dim3(BATCH), dim3(HD), 0, stream, gi1, wl, b_hh1, h1, 0);
        for (int t = 0; t < SEQ; ++t) {
            hipLaunchKernelGGL(gemm_gi2_kernel, dim3(BATCH / 64, HD3 / 64), dim3(256), 0, stream,
                               h1, W_ih2, b_ih2, gi2);
            hipLaunchKernelGGL(gemm_q_kernel, dim3(BATCH / 32, HD / 32), dim3(256), 0, stream,
                               gi2, b_hh2, W_q, qb);
            hipLaunchKernelGGL(score_kernel, dim3(BATCH), dim3(256), 0, stream,
                               P, PW, qb, v, rem, sel, pi, ll, wl, b_hh1, h1, t, (t < SEQ - 1) ? 1 : 0);
        }
    } else {
        // fallback: refb only; per-step gather-GEMM for gi1
        hipLaunchKernelGGL(gemm_bias_kernel, dim3(BATCH * SEQ / 64, HD / 64), dim3(256), 0, stream,
                           enc, HD, Bc, PW, biasc, refb, HD);
        for (int t = 0; t < SEQ; ++t) {
            hipLaunchKernelGGL(gemm_gather_kernel, dim3(BATCH / 64, HD3 / 64), dim3(256), 0, stream,
                               enc, meanenc, sel, Bc + HD, biasc + HD, gi1, t);
            hipLaunchKernelGGL(h1_kernel, dim3(BATCH), dim3(HD), 0, stream, gi1, wl, b_hh1, h1, t);
            hipLaunchKernelGGL(gemm_gi2_kernel, dim3(BATCH / 64, HD3 / 64), dim3(256), 0, stream,
                               h1, W_ih2, b_ih2, gi2);
            hipLaunchKernelGGL(gemm_q_kernel, dim3(BATCH / 32, HD / 32), dim3(256), 0, stream,
                               gi2, b_hh2, W_q, qb);
            hipLaunchKernelGGL(score_kernel, dim3(BATCH), dim3(256), 0, stream,
                               refb, HD, qb, v, rem, sel, pi, ll, wl, b_hh1, h1, t, 0);
        }
    }
    hipLaunchKernelGGL(final_kernel, dim3(BATCH), dim3(128), 0, stream, x, pi, ll, out);
}

// Round 3
// 7437.060 us; speedup vs baseline: 1.3351x; 1.0010x over previous
//
#include <hip/hip_runtime.h>
#include <cstdint>
#include <cmath>

#define BATCH 1024
#define SEQ   100
#define HD    256
#define HD3   768
#define PW    1024   // row width of fused P = [ref(256) | G1(768)]

__device__ __forceinline__ float sigmoidf_(float x) { return 1.0f / (1.0f + expf(-x)); }

// GRU cell with h=0: out = (1-z)*n ; gh == b_hh (constant)
__device__ __forceinline__ float gru0(float gr, float gz, float gn, float hr, float hz, float hn) {
    float r = sigmoidf_(gr + hr);
    float z = sigmoidf_(gz + hz);
    float n = tanhf(gn + r * hn);
    return (1.0f - z) * n;
}

// ---------------- init: mean over N of encoder rows, rem list, zero ll ----------------
__global__ __launch_bounds__(256) void init_mean_kernel(const float* __restrict__ enc,
                                                        float* __restrict__ meanenc,
                                                        int* __restrict__ rem,
                                                        float* __restrict__ ll) {
    int b = blockIdx.x, tid = threadIdx.x;
    const float* e = enc + (size_t)b * SEQ * HD + tid;
    float s = 0.f;
    for (int n = 0; n < SEQ; ++n) s += e[(size_t)n * HD];
    meanenc[(size_t)b * HD + tid] = s * (1.0f / SEQ);
    if (tid < SEQ) rem[b * SEQ + tid] = tid;
    if (tid == 0) ll[b] = 0.f;
}

// ---- prep: Bc = [W_ref | W1^T] (k-major), biasc, wl, and per-thread float4 weight packs ----
// W1p4[k*256+t] = (W_ih1[t][k], W_ih1[t+256][k], W_ih1[t+512][k], 0)   (W_ih1 ld=257)
// W2p4[k*256+t] = (W_ih2[t][k], W_ih2[t+256][k], W_ih2[t+512][k], 0)   (W_ih2 ld=256)
__global__ __launch_bounds__(256) void prep_kernel(const float* __restrict__ W_ref,
                                                   const float* __restrict__ W_ih1,
                                                   const float* __restrict__ W_ih2,
                                                   const float* __restrict__ b_ih1,
                                                   float* __restrict__ Bc,
                                                   float* __restrict__ biasc,
                                                   float* __restrict__ wl,
                                                   float4* __restrict__ W1p4,
                                                   float4* __restrict__ W2p4) {
    int k = blockIdx.x, tid = threadIdx.x;
    Bc[(size_t)k * PW + tid] = W_ref[(size_t)k * HD + tid];
#pragma unroll
    for (int c = 0; c < 3; ++c) {
        int j = c * HD + tid;
        Bc[(size_t)k * PW + HD + j] = W_ih1[(size_t)j * (HD + 1) + k];
    }
    W1p4[k * HD + tid] = make_float4(W_ih1[(size_t)tid * (HD + 1) + k],
                                     W_ih1[(size_t)(tid + HD) * (HD + 1) + k],
                                     W_ih1[(size_t)(tid + 2 * HD) * (HD + 1) + k], 0.f);
    W2p4[k * HD + tid] = make_float4(W_ih2[(size_t)tid * HD + k],
                                     W_ih2[(size_t)(tid + HD) * HD + k],
                                     W_ih2[(size_t)(tid + 2 * HD) * HD + k], 0.f);
    if (k == 0) {
        biasc[tid] = 0.f;
#pragma unroll
        for (int c = 0; c < 3; ++c) {
            int j = c * HD + tid;
            biasc[HD + j] = b_ih1[j];
            wl[j] = W_ih1[(size_t)j * (HD + 1) + HD];
        }
    }
}

// ------------- generic C = A(lda) @ B(ldb, K x N) + bias, K=256, 64x64 tiles -------------
__global__ __launch_bounds__(256) void gemm_bias_kernel(const float* __restrict__ A, int lda,
                                                        const float* __restrict__ Bm, int ldb,
                                                        const float* __restrict__ bias,
                                                        float* __restrict__ C, int ldc) {
    __shared__ float As[16][68];
    __shared__ float Bs[16][68];
    const int tid = threadIdx.x;
    const int tx = tid & 15, ty = tid >> 4;
    const int mBase = blockIdx.x * 64, nBase = blockIdx.y * 64;
    const int lr = tid >> 2, lc = (tid & 3) << 2;
    const int bkk = tid >> 4, bn4 = (tid & 15) << 2;
    float acc[4][4] = {};
    for (int k0 = 0; k0 < HD; k0 += 16) {
        float4 av = *(const float4*)&A[(size_t)(mBase + lr) * lda + k0 + lc];
        As[lc + 0][lr] = av.x; As[lc + 1][lr] = av.y; As[lc + 2][lr] = av.z; As[lc + 3][lr] = av.w;
        float4 bv = *(const float4*)&Bm[(size_t)(k0 + bkk) * ldb + nBase + bn4];
        *(float4*)&Bs[bkk][bn4] = bv;
        __syncthreads();
#pragma unroll
        for (int kk = 0; kk < 16; ++kk) {
            const float4 a4 = *(const float4*)&As[kk][ty << 2];
            const float4 b4 = *(const float4*)&Bs[kk][tx << 2];
            const float ar_[4] = {a4.x, a4.y, a4.z, a4.w};
            const float br_[4] = {b4.x, b4.y, b4.z, b4.w};
#pragma unroll
            for (int i = 0; i < 4; ++i)
#pragma unroll
                for (int j = 0; j < 4; ++j) acc[i][j] = fmaf(ar_[i], br_[j], acc[i][j]);
        }
        __syncthreads();
    }
#pragma unroll
    for (int i = 0; i < 4; ++i) {
        float o[4];
#pragma unroll
        for (int j = 0; j < 4; ++j) o[j] = acc[i][j] + bias[nBase + (tx << 2) + j];
        *(float4*)&C[(size_t)(mBase + (ty << 2) + i) * ldc + nBase + (tx << 2)] =
            make_float4(o[0], o[1], o[2], o[3]);
    }
}

// ================= fused decode: 1 kernel, 100 steps, block owns 4 b's =================
__global__ __launch_bounds__(256) void decode_kernel(const float* __restrict__ P,
                                                     const float* __restrict__ meanenc,
                                                     const float4* __restrict__ W1p4,
                                                     const float4* __restrict__ W2p4,
                                                     const float* __restrict__ W_q,
                                                     const float* __restrict__ b_ih1,
                                                     const float* __restrict__ b_hh1,
                                                     const float* __restrict__ b_ih2,
                                                     const float* __restrict__ b_hh2,
                                                     const float* __restrict__ wl,
                                                     const float* __restrict__ vvec,
                                                     const float* __restrict__ x,
                                                     float* __restrict__ out) {
    __shared__ float wls[HD3], bi1s[HD3], bhh1s[HD3], bi2s[HD3], bhh2s[HD3];
    __shared__ float vs[HD];
    __shared__ float h1s[4][HD];
    __shared__ float h2s[4][HD];
    __shared__ float qs[4][HD];
    __shared__ float us[4][SEQ];
    __shared__ int   rem_s[4][SEQ];
    __shared__ int   pi_s[4][SEQ];
    __shared__ float ll_s[4];

    const int blk = blockIdx.x, tid = threadIdx.x;
    const int w = tid >> 6, lane = tid & 63;
    const int b0 = blk << 2;

#pragma unroll
    for (int s = 0; s < 3; ++s) {
        int j = s * HD + tid;
        wls[j] = wl[j];
        bi1s[j] = b_ih1[j];
        bhh1s[j] = b_hh1[j];
        bi2s[j] = b_ih2[j];
        bhh2s[j] = b_hh2[j];
    }
    vs[tid] = vvec[tid];
    if (tid < SEQ) {
#pragma unroll
        for (int bb = 0; bb < 4; ++bb) rem_s[bb][tid] = tid;
    }
    if (tid < 4) ll_s[tid] = 0.f;
#pragma unroll
    for (int bb = 0; bb < 4; ++bb) h1s[bb][tid] = meanenc[(size_t)(b0 + bb) * HD + tid];
    __syncthreads();

    // ---- phase 0: gi1_0 = ctx0 @ W1^T (+ b_ih1 + 1.0*wl), gru1 -> h1s ----
    {
        float acc[4][3] = {};
        const float4* wp = W1p4 + tid;
#pragma unroll 2
        for (int k = 0; k < HD; k += 2) {
            float4 wa = wp[k << 8];
            float4 wb = wp[(k + 1) << 8];
            const float wav[3] = {wa.x, wa.y, wa.z};
            const float wbv[3] = {wb.x, wb.y, wb.z};
#pragma unroll
            for (int bb = 0; bb < 4; ++bb) {
                float2 h = *(const float2*)&h1s[bb][k];
#pragma unroll
                for (int s = 0; s < 3; ++s) {
                    acc[bb][s] = fmaf(h.x, wav[s], acc[bb][s]);
                    acc[bb][s] = fmaf(h.y, wbv[s], acc[bb][s]);
                }
            }
        }
        __syncthreads();
#pragma unroll
        for (int bb = 0; bb < 4; ++bb) {
            float gr = acc[bb][0] + bi1s[tid] + wls[tid];
            float gz = acc[bb][1] + bi1s[tid + HD] + wls[tid + HD];
            float gn = acc[bb][2] + bi1s[tid + 2 * HD] + wls[tid + 2 * HD];
            h1s[bb][tid] = gru0(gr, gz, gn, bhh1s[tid], bhh1s[tid + HD], bhh1s[tid + 2 * HD]);
        }
        __syncthreads();
    }

    float Dreg = 1.0f;
    const float invN = 1.0f / SEQ;

    for (int t = 0; t < SEQ; ++t) {
        const int cnt = SEQ - t;
        // ---- phase A: gi2 = h1 @ W2^T ; gates land in-thread ; gru2 -> h2s ----
        {
            float acc[4][3] = {};
            const float4* wp = W2p4 + tid;
#pragma unroll 2
            for (int k = 0; k < HD; k += 2) {
                float4 wa = wp[k << 8];
                float4 wb = wp[(k + 1) << 8];
                const float wav[3] = {wa.x, wa.y, wa.z};
                const float wbv[3] = {wb.x, wb.y, wb.z};
#pragma unroll
                for (int bb = 0; bb < 4; ++bb) {
                    float2 h = *(const float2*)&h1s[bb][k];
#pragma unroll
                    for (int s = 0; s < 3; ++s) {
                        acc[bb][s] = fmaf(h.x, wav[s], acc[bb][s]);
                        acc[bb][s] = fmaf(h.y, wbv[s], acc[bb][s]);
                    }
                }
            }
#pragma unroll
            for (int bb = 0; bb < 4; ++bb) {
                float gr = acc[bb][0] + bi2s[tid];
                float gz = acc[bb][1] + bi2s[tid + HD];
                float gn = acc[bb][2] + bi2s[tid + 2 * HD];
                h2s[bb][tid] = gru0(gr, gz, gn, bhh2s[tid], bhh2s[tid + HD], bhh2s[tid + 2 * HD]);
            }
        }
        __syncthreads();
        // ---- phase B: q = h2 @ W_q -> qs ----
        {
            float qa[4] = {};
            const float* wq = W_q + tid;
#pragma unroll 2
            for (int k = 0; k < HD; k += 2) {
                float w0 = wq[k << 8];
                float w1 = wq[(k + 1) << 8];
#pragma unroll
                for (int bb = 0; bb < 4; ++bb) {
                    float2 h = *(const float2*)&h2s[bb][k];
                    qa[bb] = fmaf(h.x, w0, qa[bb]);
                    qa[bb] = fmaf(h.y, w1, qa[bb]);
                }
            }
#pragma unroll
            for (int bb = 0; bb < 4; ++bb) qs[bb][tid] = qa[bb];
        }
        __syncthreads();
        // ---- phase C: per-wave score/argmax/softmax/update for b = b0 + w ----
        {
            const int b = b0 + w;
            const float4 qv = *(const float4*)&qs[w][lane << 2];
            const float4 vv = *(const float4*)&vs[lane << 2];
            const float* Pb = P + (size_t)b * SEQ * PW;
            int j = 0;
            for (; j + 2 <= cnt; j += 2) {
                int n0 = rem_s[w][j], n1 = rem_s[w][j + 1];
                const float4 r0 = *(const float4*)&Pb[(size_t)n0 * PW + (lane << 2)];
                const float4 r1 = *(const float4*)&Pb[(size_t)n1 * PW + (lane << 2)];
                float s0 = tanhf(qv.x + r0.x) * vv.x;
                float s1 = tanhf(qv.x + r1.x) * vv.x;
                s0 = fmaf(tanhf(qv.y + r0.y), vv.y, s0);
                s1 = fmaf(tanhf(qv.y + r1.y), vv.y, s1);
                s0 = fmaf(tanhf(qv.z + r0.z), vv.z, s0);
                s1 = fmaf(tanhf(qv.z + r1.z), vv.z, s1);
                s0 = fmaf(tanhf(qv.w + r0.w), vv.w, s0);
                s1 = fmaf(tanhf(qv.w + r1.w), vv.w, s1);
#pragma unroll
                for (int o = 1; o < 64; o <<= 1) {
                    s0 += __shfl_xor(s0, o, 64);
                    s1 += __shfl_xor(s1, o, 64);
                }
                if (lane == 0) {
                    us[w][j] = 10.0f * tanhf(s0);
                    us[w][j + 1] = 10.0f * tanhf(s1);
                }
            }
            if (j < cnt) {
                int n0 = rem_s[w][j];
                const float4 r0 = *(const float4*)&Pb[(size_t)n0 * PW + (lane << 2)];
                float s0 = tanhf(qv.x + r0.x) * vv.x;
                s0 = fmaf(tanhf(qv.y + r0.y), vv.y, s0);
                s0 = fmaf(tanhf(qv.z + r0.z), vv.z, s0);
                s0 = fmaf(tanhf(qv.w + r0.w), vv.w, s0);
#pragma unroll
                for (int o = 1; o < 64; o <<= 1) s0 += __shfl_xor(s0, o, 64);
                if (lane == 0) us[w][j] = 10.0f * tanhf(s0);
            }
            // wave argmax (first-index tie) + softmax denom
            float va = (lane < cnt) ? us[w][lane] : -3.0e38f;
            int ia = lane;
            if (lane + 64 < cnt) {
                float vb2 = us[w][lane + 64];
                if (vb2 > va) { va = vb2; ia = lane + 64; }
            }
#pragma unroll
            for (int o = 1; o < 64; o <<= 1) {
                float ov = __shfl_xor(va, o, 64);
                int oi = __shfl_xor(ia, o, 64);
                if (ov > va || (ov == va && oi < ia)) { va = ov; ia = oi; }
            }
            float e = ((lane < cnt) ? expf(us[w][lane] - va) : 0.0f) +
                      ((lane + 64 < cnt) ? expf(us[w][lane + 64] - va) : 0.0f);
#pragma unroll
            for (int o = 1; o < 64; o <<= 1) e += __shfl_xor(e, o, 64);
            const int nsel = rem_s[w][ia];     // all lanes read BEFORE lane0's swap-remove
            if (lane == 0) {
                ll_s[w] += -logf(e);           // u[sel]==max -> log_softmax[sel] = -log(sum)
                pi_s[w][t] = nsel;
                rem_s[w][ia] = rem_s[w][cnt - 1];
            }
            // h1 epilogue for step t+1 (uses D after t+1 subtractions)
            Dreg -= invN;
            if (t < SEQ - 1) {
                const float* g1 = Pb + (size_t)nsel * PW + HD;
                const int e4 = lane << 2;
                const float4 gr4 = *(const float4*)&g1[e4];
                const float4 gz4 = *(const float4*)&g1[HD + e4];
                const float4 gn4 = *(const float4*)&g1[2 * HD + e4];
                const float grv[4] = {gr4.x, gr4.y, gr4.z, gr4.w};
                const float gzv[4] = {gz4.x, gz4.y, gz4.z, gz4.w};
                const float gnv[4] = {gn4.x, gn4.y, gn4.z, gn4.w};
#pragma unroll
                for (int s = 0; s < 4; ++s) {
                    int el = e4 + s;
                    float gr = grv[s] + Dreg * wls[el];
                    float gz = gzv[s] + Dreg * wls[el + HD];
                    float gn = gnv[s] + Dreg * wls[el + 2 * HD];
                    h1s[w][el] = gru0(gr, gz, gn, bhh1s[el], bhh1s[el + HD], bhh1s[el + 2 * HD]);
                }
            }
        }
        __syncthreads();
    }

    // ---- final: tour cost + outputs (per wave, own b) ----
    {
        const int b = b0 + w;
        float d = 0.f;
        for (int e = lane; e < SEQ; e += 64) {
            int p = pi_s[w][e];
            int pn = pi_s[w][(e == SEQ - 1) ? 0 : e + 1];
            float xa = x[((size_t)b * SEQ + p) * 2 + 0];
            float ya = x[((size_t)b * SEQ + p) * 2 + 1];
            float xb2 = x[((size_t)b * SEQ + pn) * 2 + 0];
            float yb2 = x[((size_t)b * SEQ + pn) * 2 + 1];
            float dx = xa - xb2, dy = ya - yb2;
            d += sqrtf(dx * dx + dy * dy);
        }
#pragma unroll
        for (int o = 1; o < 64; o <<= 1) d += __shfl_xor(d, o, 64);
        if (lane == 0) {
            out[b] = d;
            out[BATCH + b] = ll_s[w];
        }
    }
}

// ===================== fallback path kernels (R2, ws too small for P) =====================
__global__ __launch_bounds__(256) void gemm_gather_kernel(const float* __restrict__ enc,
                                                          const float* __restrict__ meanenc,
                                                          const int* __restrict__ sel,
                                                          const float* __restrict__ Bm,
                                                          const float* __restrict__ bias,
                                                          float* __restrict__ C, int t) {
    __shared__ float As[16][68];
    __shared__ float Bs[16][68];
    const int tid = threadIdx.x;
    const int tx = tid & 15, ty = tid >> 4;
    const int mBase = blockIdx.x * 64, nBase = blockIdx.y * 64;
    const int lr = tid >> 2, lc = (tid & 3) << 2;
    const int brow = mBase + lr;
    const float* arow = (t == 0) ? (meanenc + (size_t)brow * HD)
                                 : (enc + ((size_t)brow * SEQ + sel[brow]) * HD);
    const int bkk = tid >> 4, bn4 = (tid & 15) << 2;
    float acc[4][4] = {};
    for (int k0 = 0; k0 < HD; k0 += 16) {
        float4 av = *(const float4*)&arow[k0 + lc];
        As[lc + 0][lr] = av.x; As[lc + 1][lr] = av.y; As[lc + 2][lr] = av.z; As[lc + 3][lr] = av.w;
        float4 bv = *(const float4*)&Bm[(size_t)(k0 + bkk) * PW + nBase + bn4];
        *(float4*)&Bs[bkk][bn4] = bv;
        __syncthreads();
#pragma unroll
        for (int kk = 0; kk < 16; ++kk) {
            const float4 a4 = *(const float4*)&As[kk][ty << 2];
            const float4 b4 = *(const float4*)&Bs[kk][tx << 2];
            const float ar_[4] = {a4.x, a4.y, a4.z, a4.w};
            const float br_[4] = {b4.x, b4.y, b4.z, b4.w};
#pragma unroll
            for (int i = 0; i < 4; ++i)
#pragma unroll
                for (int j = 0; j < 4; ++j) acc[i][j] = fmaf(ar_[i], br_[j], acc[i][j]);
        }
        __syncthreads();
    }
#pragma unroll
    for (int i = 0; i < 4; ++i) {
        float o[4];
#pragma unroll
        for (int j = 0; j < 4; ++j) o[j] = acc[i][j] + bias[nBase + (tx << 2) + j];
        *(float4*)&C[(size_t)(mBase + (ty << 2) + i) * HD3 + nBase + (tx << 2)] =
            make_float4(o[0], o[1], o[2], o[3]);
    }
}

__global__ __launch_bounds__(256) void h1_kernel(const float* __restrict__ gi1,
                                                 const float* __restrict__ wl,
                                                 const float* __restrict__ bhh1,
                                                 float* __restrict__ h1, int t) {
    const int b = blockIdx.x, tid = threadIdx.x;
    float D = 1.0f;
    const float invN = 1.0f / SEQ;
    for (int i = 0; i < t; ++i) D -= invN;
    const float* g = gi1 + (size_t)b * HD3;
    float gr = g[tid] + D * wl[tid];
    float gz = g[tid + HD] + D * wl[tid + HD];
    float gn = g[tid + 2 * HD] + D * wl[tid + 2 * HD];
    h1[(size_t)b * HD + tid] = gru0(gr, gz, gn, bhh1[tid], bhh1[tid + HD], bhh1[tid + 2 * HD]);
}

__global__ __launch_bounds__(256) void gemm_gi2_kernel(const float* __restrict__ h1,
                                                       const float* __restrict__ W_ih2,
                                                       const float* __restrict__ b_ih2,
                                                       float* __restrict__ gi2) {
    __shared__ float As[16][68];
    __shared__ float Bs[16][68];
    const int tid = threadIdx.x;
    const int tx = tid & 15, ty = tid >> 4;
    const int mBase = blockIdx.x * 64, nBase = blockIdx.y * 64;
    const int lr = tid >> 2, lc = (tid & 3) << 2;
    float acc[4][4] = {};
    for (int k0 = 0; k0 < HD; k0 += 16) {
        float4 av = *(const float4*)&h1[(size_t)(mBase + lr) * HD + k0 + lc];
        As[lc + 0][lr] = av.x; As[lc + 1][lr] = av.y; As[lc + 2][lr] = av.z; As[lc + 3][lr] = av.w;
        float4 bv = *(const float4*)&W_ih2[(size_t)(nBase + lr) * HD + k0 + lc];
        Bs[lc + 0][lr] = bv.x; Bs[lc + 1][lr] = bv.y; Bs[lc + 2][lr] = bv.z; Bs[lc + 3][lr] = bv.w;
        __syncthreads();
#pragma unroll
        for (int kk = 0; kk < 16; ++kk) {
            const float4 a4 = *(const float4*)&As[kk][ty << 2];
            const float4 b4 = *(const float4*)&Bs[kk][tx << 2];
            const float ar_[4] = {a4.x, a4.y, a4.z, a4.w};
            const float br_[4] = {b4.x, b4.y, b4.z, b4.w};
#pragma unroll
            for (int i = 0; i < 4; ++i)
#pragma unroll
                for (int j = 0; j < 4; ++j) acc[i][j] = fmaf(ar_[i], br_[j], acc[i][j]);
        }
        __syncthreads();
    }
#pragma unroll
    for (int i = 0; i < 4; ++i) {
        float o[4];
#pragma unroll
        for (int j = 0; j < 4; ++j) o[j] = acc[i][j] + b_ih2[nBase + (tx << 2) + j];
        *(float4*)&gi2[(size_t)(mBase + (ty << 2) + i) * HD3 + nBase + (tx << 2)] =
            make_float4(o[0], o[1], o[2], o[3]);
    }
}

__global__ __launch_bounds__(256) void gemm_q_kernel(const float* __restrict__ gi2,
                                                     const float* __restrict__ b_hh2,
                                                     const float* __restrict__ W_q,
                                                     float* __restrict__ qb) {
    __shared__ float As[32][36];
    __shared__ float Bs[32][36];
    const int tid = threadIdx.x;
    const int tx = tid & 15, ty = tid >> 4;
    const int mBase = blockIdx.x * 32, nBase = blockIdx.y * 32;
    const int ar = tid >> 3, ac = (tid & 7) << 2;
    float acc[2][2] = {};
    for (int k0 = 0; k0 < HD; k0 += 32) {
        const float* g = gi2 + (size_t)(mBase + ar) * HD3 + k0 + ac;
        float4 gr = *(const float4*)&g[0];
        float4 gz = *(const float4*)&g[HD];
        float4 gn = *(const float4*)&g[2 * HD];
        float4 hr = *(const float4*)&b_hh2[k0 + ac];
        float4 hz = *(const float4*)&b_hh2[HD + k0 + ac];
        float4 hn = *(const float4*)&b_hh2[2 * HD + k0 + ac];
        As[ac + 0][ar] = gru0(gr.x, gz.x, gn.x, hr.x, hz.x, hn.x);
        As[ac + 1][ar] = gru0(gr.y, gz.y, gn.y, hr.y, hz.y, hn.y);
        As[ac + 2][ar] = gru0(gr.z, gz.z, gn.z, hr.z, hz.z, hn.z);
        As[ac + 3][ar] = gru0(gr.w, gz.w, gn.w, hr.w, hz.w, hn.w);
        float4 bv = *(const float4*)&W_q[(size_t)(k0 + ar) * HD + nBase + ac];
        *(float4*)&Bs[ar][ac] = bv;
        __syncthreads();
#pragma unroll
        for (int kk = 0; kk < 32; ++kk) {
            const float2 a2 = *(const float2*)&As[kk][ty << 1];
            const float2 b2 = *(const float2*)&Bs[kk][tx << 1];
            acc[0][0] = fmaf(a2.x, b2.x, acc[0][0]);
            acc[0][1] = fmaf(a2.x, b2.y, acc[0][1]);
            acc[1][0] = fmaf(a2.y, b2.x, acc[1][0]);
            acc[1][1] = fmaf(a2.y, b2.y, acc[1][1]);
        }
        __syncthreads();
    }
#pragma unroll
    for (int i = 0; i < 2; ++i) {
        *(float2*)&qb[(size_t)(mBase + (ty << 1) + i) * HD + nBase + (tx << 1)] =
            make_float2(acc[i][0], acc[i][1]);
    }
}

__global__ __launch_bounds__(256) void score_kernel(const float* __restrict__ refbase, int ldref,
                                                    const float* __restrict__ qb,
                                                    const float* __restrict__ vvec,
                                                    int* __restrict__ rem,
                                                    int* __restrict__ sel,
                                                    int* __restrict__ pi,
                                                    float* __restrict__ ll, int t) {
    __shared__ float qs[HD];
    __shared__ float vs[HD];
    __shared__ float us[SEQ];
    __shared__ int ns[SEQ];
    const int b = blockIdx.x, tid = threadIdx.x;
    const int cnt = SEQ - t;
    qs[tid] = qb[(size_t)b * HD + tid];
    vs[tid] = vvec[tid];
    __syncthreads();
    const int w = tid >> 6, lane = tid & 63;
    const float4 qv = *(const float4*)&qs[lane << 2];
    const float4 vv = *(const float4*)&vs[lane << 2];
    for (int j = w; j < cnt; j += 4) {
        int n = rem[b * SEQ + j];
        const float4 rf = *(const float4*)&refbase[((size_t)b * SEQ + n) * ldref + (lane << 2)];
        float s = tanhf(qv.x + rf.x) * vv.x;
        s = fmaf(tanhf(qv.y + rf.y), vv.y, s);
        s = fmaf(tanhf(qv.z + rf.z), vv.z, s);
        s = fmaf(tanhf(qv.w + rf.w), vv.w, s);
#pragma unroll
        for (int o = 1; o < 64; o <<= 1) s += __shfl_xor(s, o, 64);
        if (lane == 0) {
            us[j] = 10.0f * tanhf(s);
            ns[j] = n;
        }
    }
    __syncthreads();
    if (tid < 64) {
        float va = (tid < cnt) ? us[tid] : -3.0e38f;
        int ia = tid;
        if (tid + 64 < cnt) {
            float vb = us[tid + 64];
            if (vb > va) { va = vb; ia = tid + 64; }
        }
#pragma unroll
        for (int o = 1; o < 64; o <<= 1) {
            float ov = __shfl_xor(va, o, 64);
            int oi = __shfl_xor(ia, o, 64);
            if (ov > va || (ov == va && oi < ia)) { va = ov; ia = oi; }
        }
        float e = ((tid < cnt) ? expf(us[tid] - va) : 0.0f) +
                  ((tid + 64 < cnt) ? expf(us[tid + 64] - va) : 0.0f);
#pragma unroll
        for (int o = 1; o < 64; o <<= 1) e += __shfl_xor(e, o, 64);
        if (tid == 0) {
            int n = ns[ia];
            ll[b] += -logf(e);
            sel[b] = n;
            pi[(size_t)b * SEQ + t] = n;
            rem[b * SEQ + ia] = rem[b * SEQ + cnt - 1];
        }
    }
}

__global__ __launch_bounds__(128) void final_kernel(const float* __restrict__ x,
                                                    const int* __restrict__ pi,
                                                    const float* __restrict__ ll,
                                                    float* __restrict__ out) {
    __shared__ float red[2];
    const int b = blockIdx.x, tid = threadIdx.x;
    const int w = tid >> 6, lane = tid & 63;
    float d = 0.f;
    if (tid < SEQ) {
        int p = pi[(size_t)b * SEQ + tid];
        int pn = pi[(size_t)b * SEQ + ((tid == SEQ - 1) ? 0 : tid + 1)];
        float xa = x[((size_t)b * SEQ + p) * 2 + 0];
        float ya = x[((size_t)b * SEQ + p) * 2 + 1];
        float xb = x[((size_t)b * SEQ + pn) * 2 + 0];
        float yb = x[((size_t)b * SEQ + pn) * 2 + 1];
        float dx = xa - xb, dy = ya - yb;
        d = sqrtf(dx * dx + dy * dy);
    }
#pragma unroll
    for (int o = 1; o < 64; o <<= 1) d += __shfl_xor(d, o, 64);
    if (lane == 0) red[w] = d;
    __syncthreads();
    if (tid == 0) {
        out[b] = red[0] + red[1];
        out[BATCH + b] = ll[b];
    }
}

extern "C" void kernel_launch(void* const* d_in, const int* in_sizes, int n_in,
                              void* d_out, int out_size, void* d_ws, size_t ws_size,
                              hipStream_t stream) {
    const float* x     = (const float*)d_in[0];
    const float* enc   = (const float*)d_in[1];
    const float* W_ih1 = (const float*)d_in[2];
    // d_in[3] = W_hh1: unused (h==0 -> gh == b_hh)
    const float* b_ih1 = (const float*)d_in[4];
    const float* b_hh1 = (const float*)d_in[5];
    const float* W_ih2 = (const float*)d_in[6];
    // d_in[7] = W_hh2: unused
    const float* b_ih2 = (const float*)d_in[8];
    const float* b_hh2 = (const float*)d_in[9];
    const float* W_q   = (const float*)d_in[10];
    const float* W_ref = (const float*)d_in[11];
    const float* v     = (const float*)d_in[12];
    float* out = (float*)d_out;
    (void)in_sizes; (void)n_in; (void)out_size;

    char* w = (char*)d_ws;
    size_t off = 0;
    auto take = [&](size_t bytes) {
        char* p = w + off;
        off = (off + bytes + 255) & ~(size_t)255;
        return p;
    };
    float*  meanenc = (float*)take((size_t)BATCH * HD * 4);
    float*  gi1     = (float*)take((size_t)BATCH * HD3 * 4);
    float*  gi2     = (float*)take((size_t)BATCH * HD3 * 4);
    float*  qb      = (float*)take((size_t)BATCH * HD * 4);
    float*  h1      = (float*)take((size_t)BATCH * HD * 4);
    float*  Bc      = (float*)take((size_t)HD * PW * 4);
    float*  biasc   = (float*)take((size_t)PW * 4);
    float*  wl      = (float*)take((size_t)HD3 * 4);
    float*  ll      = (float*)take((size_t)BATCH * 4);
    int*    sel     = (int*)take((size_t)BATCH * 4);
    int*    pi      = (int*)take((size_t)BATCH * SEQ * 4);
    int*    rem     = (int*)take((size_t)BATCH * SEQ * 4);
    float4* W1p4    = (float4*)take((size_t)HD * HD * 16);
    float4* W2p4    = (float4*)take((size_t)HD * HD * 16);

    const size_t Pbytes = (size_t)BATCH * SEQ * PW * 4;     // 419.4 MB
    const size_t Rbytes = (size_t)BATCH * SEQ * HD * 4;     // 104.9 MB
    const bool useFused = (ws_size >= off + Pbytes);
    float* P    = useFused ? (float*)take(Pbytes) : nullptr;
    float* refb = useFused ? nullptr : (float*)take(Rbytes);

    hipLaunchKernelGGL(init_mean_kernel, dim3(BATCH), dim3(HD), 0, stream, enc, meanenc, rem, ll);
    hipLaunchKernelGGL(prep_kernel, dim3(HD), dim3(HD), 0, stream,
                       W_ref, W_ih1, W_ih2, b_ih1, Bc, biasc, wl, W1p4, W2p4);

    if (useFused) {
        // P = enc @ [W_ref | W1^T] + [0 | b_ih1]   (102400 x 1024 x 256)
        hipLaunchKernelGGL(gemm_bias_kernel, dim3(BATCH * SEQ / 64, PW / 64), dim3(256), 0, stream,
                           enc, HD, Bc, PW, biasc, P, PW);
        // one kernel = whole 100-step decode + cost
        hipLaunchKernelGGL(decode_kernel, dim3(BATCH / 4), dim3(256), 0, stream,
                           P, meanenc, W1p4, W2p4, W_q, b_ih1, b_hh1, b_ih2, b_hh2,
                           wl, v, x, out);
    } else {
        hipLaunchKernelGGL(gemm_bias_kernel, dim3(BATCH * SEQ / 64, HD / 64), dim3(256), 0, stream,
                           enc, HD, Bc, PW, biasc, refb, HD);
        for (int t = 0; t < SEQ; ++t) {
            hipLaunchKernelGGL(gemm_gather_kernel, dim3(BATCH / 64, HD3 / 64), dim3(256), 0, stream,
                               enc, meanenc, sel, Bc + HD, biasc + HD, gi1, t);
            hipLaunchKernelGGL(h1_kernel, dim3(BATCH), dim3(HD), 0, stream, gi1, wl, b_hh1, h1, t);
            hipLaunchKernelGGL(gemm_gi2_kernel, dim3(BATCH / 64, HD3 / 64), dim3(256), 0, stream,
                               h1, W_ih2, b_ih2, gi2);
            hipLaunchKernelGGL(gemm_q_kernel, dim3(BATCH / 32, HD / 32), dim3(256), 0, stream,
                               gi2, b_hh2, W_q, qb);
            hipLaunchKernelGGL(score_kernel, dim3(BATCH), dim3(256), 0, stream,
                               refb, HD, qb, v, rem, sel, pi, ll, t);
        }
        hipLaunchKernelGGL(final_kernel, dim3(BATCH), dim3(128), 0, stream, x, pi, ll, out);
    }
}